// Round 1
// baseline (349.437 us; speedup 1.0000x reference)
//
#include <hip/hip_runtime.h>
#include <math.h>

#define DIM 512
#define INTER 64
#define N_SHARED 2
#define N_ROUTED 64
#define TOPK 6
#define NTOK 1024            // B*T = 2*512
#define KSLOTS 8             // N_SHARED + TOPK

// ---------------------------------------------------------------------------
// Gate: one wave (64 lanes) per token. Lane e computes routed logit e.
// Softmax over 64 lanes, then 6x iterative argmax on (prob + bias) with
// first-index tie-break (matches jax.lax.top_k). Writes 8 slots per token:
// slot 0,1 = shared experts (weight 1.0), slots 2..7 = routed (weight = prob).
// ---------------------------------------------------------------------------
__global__ __launch_bounds__(64) void gate_kernel(
    const float* __restrict__ x,
    const float* __restrict__ g_w,
    const float* __restrict__ gate_bias,
    int* __restrict__ slots,
    float* __restrict__ sweights) {
  const int t = blockIdx.x;
  const int lane = threadIdx.x;                 // 0..63 == routed expert id
  const float* xr = x + (size_t)t * DIM;
  const float* gw = g_w + (size_t)lane * DIM;

  float acc = 0.f;
  for (int d = 0; d < DIM; d += 4) {
    float4 xv = *(const float4*)(xr + d);
    float4 wv = *(const float4*)(gw + d);
    acc += xv.x * wv.x + xv.y * wv.y + xv.z * wv.z + xv.w * wv.w;
  }

  // softmax across the 64 lanes
  float m = acc;
  for (int off = 32; off > 0; off >>= 1) m = fmaxf(m, __shfl_xor(m, off, 64));
  float p = expf(acc - m);
  float s = p;
  for (int off = 32; off > 0; off >>= 1) s += __shfl_xor(s, off, 64);
  const float prob = p / s;

  float biased = prob + gate_bias[lane];

  // top-6 via iterative argmax (butterfly reduce, smaller index wins ties)
  for (int k = 0; k < TOPK; ++k) {
    float v = biased;
    int idx = lane;
    for (int off = 1; off < 64; off <<= 1) {
      float ov = __shfl_xor(v, off, 64);
      int oi = __shfl_xor(idx, off, 64);
      if (ov > v || (ov == v && oi < idx)) { v = ov; idx = oi; }
    }
    float w = __shfl(prob, idx, 64);
    if (lane == 0) {
      slots[t * KSLOTS + N_SHARED + k] = idx + N_SHARED;
      sweights[t * KSLOTS + N_SHARED + k] = w;   // ROUTE_SCALE == 1.0
    }
    if (lane == idx) biased = -INFINITY;
  }
  if (lane == 0) {
    slots[t * KSLOTS + 0] = 0; sweights[t * KSLOTS + 0] = 1.f;
    slots[t * KSLOTS + 1] = 1; sweights[t * KSLOTS + 1] = 1.f;
  }
}

// ---------------------------------------------------------------------------
// Expert FFN: one block (256 threads) per token; loops over the token's 8
// slots. h1/h3: 4 groups of 64 lanes, lane i handles inter-unit i over a
// 128-wide d-slice (coalesced 256B reads of w1/w3), LDS-reduced. Then the
// w2 combine: each thread owns 2 output dims, accumulates across slots in
// registers (no atomics), single coalesced store at the end.
// ---------------------------------------------------------------------------
__global__ __launch_bounds__(256) void ffn_kernel(
    const float* __restrict__ x,
    const float* __restrict__ w1,
    const float* __restrict__ w2,
    const float* __restrict__ w3,
    const int* __restrict__ slots,
    const float* __restrict__ sweights,
    float* __restrict__ out) {
  __shared__ float xs[DIM];
  __shared__ float part1[4][INTER];
  __shared__ float part3[4][INTER];
  __shared__ float as[INTER];

  const int t = blockIdx.x;
  const int tid = threadIdx.x;
  const int i = tid & 63;    // inter-unit
  const int g = tid >> 6;    // d-group (0..3)

  {
    float2 v = *(const float2*)(x + (size_t)t * DIM + tid * 2);
    xs[tid * 2] = v.x;
    xs[tid * 2 + 1] = v.y;
  }
  __syncthreads();

  float acc0 = 0.f, acc1 = 0.f;   // output dims tid and tid+256

  for (int s = 0; s < KSLOTS; ++s) {
    const int e = slots[t * KSLOTS + s];
    const float cw = sweights[t * KSLOTS + s];
    const float* w1e = w1 + (size_t)e * DIM * INTER;
    const float* w3e = w3 + (size_t)e * DIM * INTER;

    float p1 = 0.f, p3 = 0.f;
    const int d0 = g * 128;
    #pragma unroll 4
    for (int d = d0; d < d0 + 128; ++d) {
      const float xv = xs[d];
      p1 += xv * w1e[d * INTER + i];
      p3 += xv * w3e[d * INTER + i];
    }
    part1[g][i] = p1;
    part3[g][i] = p3;
    __syncthreads();

    if (tid < INTER) {
      const float h1 = part1[0][tid] + part1[1][tid] + part1[2][tid] + part1[3][tid];
      const float h3 = part3[0][tid] + part3[1][tid] + part3[2][tid] + part3[3][tid];
      const float sig = 1.f / (1.f + expf(-h1));
      as[tid] = h1 * sig * h3;
    }
    __syncthreads();

    const float* w2e = w2 + (size_t)e * INTER * DIM;
    float o0 = 0.f, o1 = 0.f;
    #pragma unroll 8
    for (int ii = 0; ii < INTER; ++ii) {
      const float a = as[ii];
      o0 += a * w2e[ii * DIM + tid];
      o1 += a * w2e[ii * DIM + tid + 256];
    }
    acc0 += cw * o0;
    acc1 += cw * o1;
    __syncthreads();   // protect part1/part3/as before next slot overwrites
  }

  out[(size_t)t * DIM + tid] = acc0;
  out[(size_t)t * DIM + tid + 256] = acc1;
}

extern "C" void kernel_launch(void* const* d_in, const int* in_sizes, int n_in,
                              void* d_out, int out_size, void* d_ws, size_t ws_size,
                              hipStream_t stream) {
  const float* x         = (const float*)d_in[0];
  const float* g_w       = (const float*)d_in[1];
  const float* gate_bias = (const float*)d_in[2];
  const float* w1        = (const float*)d_in[3];
  const float* w2        = (const float*)d_in[4];
  const float* w3        = (const float*)d_in[5];
  float* out = (float*)d_out;

  int*   slots    = (int*)d_ws;
  float* sweights = (float*)((char*)d_ws + (size_t)NTOK * KSLOTS * sizeof(int));

  gate_kernel<<<NTOK, 64, 0, stream>>>(x, g_w, gate_bias, slots, sweights);
  ffn_kernel<<<NTOK, 256, 0, stream>>>(x, w1, w2, w3, slots, sweights, out);
}

// Round 2
// 198.237 us; speedup vs baseline: 1.7627x; 1.7627x over previous
//
#include <hip/hip_runtime.h>
#include <math.h>

#define DIM 512
#define INTER 64
#define N_ROUTED 64
#define TOPK 6
#define NTOK 1024            // B*T
#define CAP 1024             // per-expert token list capacity (max possible)
#define TTILE 16             // tokens per block tile
#define GR 8                 // token-groups per routed expert
#define GS 64                // token-groups per shared expert

// ---------------------------------------------------------------------------
// Transpose g_w [64][512] -> g_wT [512][64] so gate loads are coalesced.
// ---------------------------------------------------------------------------
__global__ __launch_bounds__(256) void transpose_gw(
    const float* __restrict__ g_w, float* __restrict__ g_wT) {
  __shared__ float tile[32][33];
  const int bd = blockIdx.x;          // 0..15 (d tiles)
  const int be = blockIdx.y;          // 0..1  (e tiles)
  const int c = threadIdx.x & 31;
  const int r = threadIdx.x >> 5;     // 0..7
  #pragma unroll
  for (int k = 0; k < 4; ++k) {
    int e = be * 32 + r + k * 8;
    int d = bd * 32 + c;
    tile[r + k * 8][c] = g_w[e * DIM + d];
  }
  __syncthreads();
  #pragma unroll
  for (int k = 0; k < 4; ++k) {
    int d = bd * 32 + r + k * 8;
    int e = be * 32 + c;
    g_wT[d * N_ROUTED + e] = tile[c][r + k * 8];
  }
}

// ---------------------------------------------------------------------------
// Gate: one wave per 2 tokens, lane = routed expert. Coalesced g_wT loads.
// Softmax over 64 lanes; iterative top-6 argmax on (prob + bias), first-index
// tie-break (matches lax.top_k). Winning lane appends (token, prob) to its
// expert's list via atomic counter.
// ---------------------------------------------------------------------------
__global__ __launch_bounds__(256) void gate_kernel(
    const float* __restrict__ x, const float* __restrict__ g_wT,
    const float* __restrict__ gate_bias,
    int* __restrict__ cnt, int* __restrict__ tlist, float* __restrict__ wlist) {
  const int lane = threadIdx.x & 63;
  const int gw = (blockIdx.x * 256 + threadIdx.x) >> 6;  // global wave id 0..511
  const int t0 = gw * 2;
  const float* x0 = x + (size_t)t0 * DIM;
  const float* x1 = x0 + DIM;

  float acc0 = 0.f, acc1 = 0.f;
  for (int d = 0; d < DIM; d += 4) {
    float4 xv0 = *(const float4*)(x0 + d);
    float4 xv1 = *(const float4*)(x1 + d);
    float g0 = g_wT[(d + 0) * N_ROUTED + lane];
    float g1 = g_wT[(d + 1) * N_ROUTED + lane];
    float g2 = g_wT[(d + 2) * N_ROUTED + lane];
    float g3 = g_wT[(d + 3) * N_ROUTED + lane];
    acc0 += xv0.x * g0 + xv0.y * g1 + xv0.z * g2 + xv0.w * g3;
    acc1 += xv1.x * g0 + xv1.y * g1 + xv1.z * g2 + xv1.w * g3;
  }
  const float bias = gate_bias[lane];

  for (int tk = 0; tk < 2; ++tk) {
    const float logit = tk ? acc1 : acc0;
    const int tok = t0 + tk;
    float m = logit;
    for (int off = 32; off; off >>= 1) m = fmaxf(m, __shfl_xor(m, off, 64));
    float p = expf(logit - m);
    float s = p;
    for (int off = 32; off; off >>= 1) s += __shfl_xor(s, off, 64);
    const float prob = p / s;
    float biased = prob + bias;
    for (int k = 0; k < TOPK; ++k) {
      float v = biased;
      int idx = lane;
      for (int off = 1; off < 64; off <<= 1) {
        float ov = __shfl_xor(v, off, 64);
        int oi = __shfl_xor(idx, off, 64);
        if (ov > v || (ov == v && oi < idx)) { v = ov; idx = oi; }
      }
      if (lane == idx) {
        int pos = atomicAdd(&cnt[lane], 1);
        tlist[lane * CAP + pos] = tok;
        wlist[lane * CAP + pos] = prob;   // ROUTE_SCALE == 1.0
        biased = -INFINITY;
      }
    }
  }
}

// ---------------------------------------------------------------------------
// Expert-centric FFN: block = (expert, token-group). Stages 16 tokens' x in
// LDS, streams w1/w3/w2 once per tile (coalesced), register-accumulates
// 16-token outputs, atomicAdd scatter into zeroed out.
// grid: [0, 64*GR) routed; [64*GR, 64*GR + 2*GS) shared.
// ---------------------------------------------------------------------------
__global__ __launch_bounds__(256) void ffn_kernel(
    const float* __restrict__ x,
    const float* __restrict__ w1, const float* __restrict__ w2,
    const float* __restrict__ w3,
    const int* __restrict__ cnt, const int* __restrict__ tlist,
    const float* __restrict__ wlist,
    float* __restrict__ out) {
  __shared__ float xs[TTILE][DIM];            // 32 KB
  __shared__ float part1[4][TTILE][INTER];    // 16 KB
  __shared__ float part3[4][TTILE][INTER];    // 16 KB
  __shared__ float as_[TTILE][INTER];         // 4 KB
  __shared__ int   tok[TTILE];
  __shared__ float tw[TTILE];

  const int tid = threadIdx.x;
  int e, g, G, n;
  const bool shared_e = (blockIdx.x >= N_ROUTED * GR);
  const int* mylist = nullptr;
  const float* mywl = nullptr;
  if (!shared_e) {
    const int r = blockIdx.x >> 3;            // GR = 8
    g = blockIdx.x & 7;
    e = r + 2; G = GR; n = cnt[r];
    mylist = tlist + r * CAP;
    mywl = wlist + r * CAP;
  } else {
    const int sb = blockIdx.x - N_ROUTED * GR;
    e = sb >> 6; g = sb & 63; G = GS; n = NTOK;
  }
  const int m = (n > g) ? (n - g + G - 1) / G : 0;

  const float* w1e = w1 + (size_t)e * DIM * INTER;
  const float* w3e = w3 + (size_t)e * DIM * INTER;
  const float* w2e = w2 + (size_t)e * INTER * DIM;

  const int i = tid & 63;
  const int q = tid >> 6;
  const int d0 = q * 128;

  for (int base = 0; base < m; base += TTILE) {
    const int mt = min(TTILE, m - base);
    if (tid < TTILE) {
      if (tid < mt) {
        const int j = g + (base + tid) * G;
        if (shared_e) { tok[tid] = j; tw[tid] = 1.0f; }
        else          { tok[tid] = mylist[j]; tw[tid] = mywl[j]; }
      } else { tok[tid] = 0; tw[tid] = 0.0f; }
    }
    __syncthreads();

    // stage 16 tokens' x rows (coalesced float4)
    #pragma unroll
    for (int k = 0; k < 8; ++k) {
      const int fidx = tid + k * 256;     // 0..2047 float4 slots
      const int row = fidx >> 7;          // 128 float4 per row
      const int c4 = fidx & 127;
      *(float4*)&xs[row][c4 * 4] =
          *(const float4*)(x + (size_t)tok[row] * DIM + c4 * 4);
    }
    __syncthreads();

    // ---- h1/h3 phase: wave q covers d in [q*128, q*128+128) ----
    float p1[TTILE], p3[TTILE];
    #pragma unroll
    for (int t = 0; t < TTILE; ++t) { p1[t] = 0.f; p3[t] = 0.f; }
    for (int d = d0; d < d0 + 128; d += 4) {
      const float a0 = w1e[(d + 0) * INTER + i];
      const float a1 = w1e[(d + 1) * INTER + i];
      const float a2 = w1e[(d + 2) * INTER + i];
      const float a3 = w1e[(d + 3) * INTER + i];
      const float b0 = w3e[(d + 0) * INTER + i];
      const float b1 = w3e[(d + 1) * INTER + i];
      const float b2 = w3e[(d + 2) * INTER + i];
      const float b3 = w3e[(d + 3) * INTER + i];
      #pragma unroll
      for (int t = 0; t < TTILE; ++t) {
        const float4 xv = *(const float4*)&xs[t][d];
        p1[t] += xv.x * a0 + xv.y * a1 + xv.z * a2 + xv.w * a3;
        p3[t] += xv.x * b0 + xv.y * b1 + xv.z * b2 + xv.w * b3;
      }
    }
    #pragma unroll
    for (int t = 0; t < TTILE; ++t) {
      part1[q][t][i] = p1[t];
      part3[q][t][i] = p3[t];
    }
    __syncthreads();

    // ---- reduce quarters + silu activation ----
    #pragma unroll
    for (int k = 0; k < 4; ++k) {
      const int v = tid + k * 256;
      const int t = v >> 6, ii = v & 63;
      const float h1 = part1[0][t][ii] + part1[1][t][ii] +
                       part1[2][t][ii] + part1[3][t][ii];
      const float h3 = part3[0][t][ii] + part3[1][t][ii] +
                       part3[2][t][ii] + part3[3][t][ii];
      as_[t][ii] = (h1 / (1.0f + expf(-h1))) * h3;
    }
    __syncthreads();

    // ---- w2 combine: thread owns output cols tid and tid+256 ----
    float o0[TTILE], o1[TTILE];
    #pragma unroll
    for (int t = 0; t < TTILE; ++t) { o0[t] = 0.f; o1[t] = 0.f; }
    for (int ii = 0; ii < INTER; ii += 4) {
      const float u0 = w2e[(ii + 0) * DIM + tid];
      const float u1 = w2e[(ii + 1) * DIM + tid];
      const float u2 = w2e[(ii + 2) * DIM + tid];
      const float u3 = w2e[(ii + 3) * DIM + tid];
      const float v0 = w2e[(ii + 0) * DIM + tid + 256];
      const float v1 = w2e[(ii + 1) * DIM + tid + 256];
      const float v2 = w2e[(ii + 2) * DIM + tid + 256];
      const float v3 = w2e[(ii + 3) * DIM + tid + 256];
      #pragma unroll
      for (int t = 0; t < TTILE; ++t) {
        const float4 av = *(const float4*)&as_[t][ii];
        o0[t] += av.x * u0 + av.y * u1 + av.z * u2 + av.w * u3;
        o1[t] += av.x * v0 + av.y * v1 + av.z * v2 + av.w * v3;
      }
    }
    for (int t = 0; t < mt; ++t) {
      const float wgt = tw[t];
      atomicAdd(&out[(size_t)tok[t] * DIM + tid], wgt * o0[t]);
      atomicAdd(&out[(size_t)tok[t] * DIM + tid + 256], wgt * o1[t]);
    }
    __syncthreads();
  }
}

extern "C" void kernel_launch(void* const* d_in, const int* in_sizes, int n_in,
                              void* d_out, int out_size, void* d_ws, size_t ws_size,
                              hipStream_t stream) {
  const float* x         = (const float*)d_in[0];
  const float* g_w       = (const float*)d_in[1];
  const float* gate_bias = (const float*)d_in[2];
  const float* w1        = (const float*)d_in[3];
  const float* w2        = (const float*)d_in[4];
  const float* w3        = (const float*)d_in[5];
  float* out = (float*)d_out;

  char* ws = (char*)d_ws;
  int*   cnt   = (int*)ws;                                   // 64 ints (pad 1 KB)
  int*   tlist = (int*)(ws + 1024);                          // 64*1024 ints
  float* wlist = (float*)(ws + 1024 + N_ROUTED * CAP * 4);   // 64*1024 floats
  float* g_wT  = (float*)(ws + 1024 + N_ROUTED * CAP * 8);   // 512*64 floats

  hipMemsetAsync(out, 0, (size_t)out_size * sizeof(float), stream);
  hipMemsetAsync(cnt, 0, N_ROUTED * sizeof(int), stream);

  dim3 tg(DIM / 32, N_ROUTED / 32);
  transpose_gw<<<tg, 256, 0, stream>>>(g_w, g_wT);
  gate_kernel<<<NTOK / 8, 256, 0, stream>>>(x, g_wT, gate_bias, cnt, tlist, wlist);
  ffn_kernel<<<N_ROUTED * GR + 2 * GS, 256, 0, stream>>>(
      x, w1, w2, w3, cnt, tlist, wlist, out);
}